// Round 2
// baseline (179.885 us; speedup 1.0000x reference)
//
#include <hip/hip_runtime.h>
#include <stdint.h>

// x (8, 512, 64, 64) fp32, mask (64, 64) int32 -> out (8, 768, 64, 64) fp32
static constexpr int HW = 4096;   // 64*64
static constexpr int CC = 512;
static constexpr int C2 = 256;
static constexpr int OC = 768;

__device__ __forceinline__ uint32_t rotl32(uint32_t x, int d) {
  return (x << d) | (x >> (32 - d));
}

// JAX threefry2x32, key (0, 42)  [jax.random.key(42)]
__device__ __forceinline__ void threefry_0_42(uint32_t x0, uint32_t x1,
                                              uint32_t& o0, uint32_t& o1) {
  const uint32_t k0 = 0u;
  const uint32_t k1 = 42u;
  const uint32_t k2 = 0x1BD11BDAu ^ k0 ^ k1;   // 0x1BD11BF0
  x0 += k0; x1 += k1;
#define TF_ROUND(r) { x0 += x1; x1 = rotl32(x1, (r)); x1 ^= x0; }
  TF_ROUND(13) TF_ROUND(15) TF_ROUND(26) TF_ROUND(6)
  x0 += k1; x1 += k2 + 1u;
  TF_ROUND(17) TF_ROUND(29) TF_ROUND(16) TF_ROUND(24)
  x0 += k2; x1 += k0 + 2u;
  TF_ROUND(13) TF_ROUND(15) TF_ROUND(26) TF_ROUND(6)
  x0 += k0; x1 += k1 + 3u;
  TF_ROUND(17) TF_ROUND(29) TF_ROUND(16) TF_ROUND(24)
  x0 += k1; x1 += k2 + 4u;
  TF_ROUND(13) TF_ROUND(15) TF_ROUND(26) TF_ROUND(6)
  x0 += k2; x1 += k0 + 5u;
#undef TF_ROUND
  o0 = x0; o1 = x1;
}

// Partitionable threefry: counter (0, e), fold = xor of the two output lanes.
__device__ __forceinline__ uint32_t jax_bits32(uint32_t e) {
  uint32_t o0, o1;
  threefry_0_42(0u, e, o0, o1);
  return o0 ^ o1;
}

// ---------------------------------------------------------------------------
// Kernel A (4096 blocks, even/odd role interleave for VALU/mem co-schedule —
// the round-0 structure that worked, with the latter-copy moved to kernel B):
//   even p: copy former plane q=p/2 in [0,2048): out[b,c] = x[b,c], c<256
//   odd  p: idx role, rows {2q, 2q+1}, q=p/2 in [0,2048):
//     one ballot compaction of unflagged columns per block (amortized 2x),
//     then exact-integer threefry argmax per row.
__global__ __launch_bounds__(256) void former_idx_kernel(
    const float* __restrict__ x, const int* __restrict__ mask,
    int* __restrict__ idx, float* __restrict__ out) {
  const int p = blockIdx.x;
  if ((p & 1) == 0) {
    const int q = p >> 1;                   // 0..2047 former planes
    const int b = q >> 8, c = q & 255;
    const float4* src = (const float4*)(x + ((size_t)b * CC + c) * HW);
    float4* dst = (float4*)(out + ((size_t)b * OC + c) * HW);
#pragma unroll
    for (int r = 0; r < 4; ++r) {
      const int t = threadIdx.x + r * 256;
      dst[t] = src[t];
    }
    return;
  }

  // ---- idx role ----
  __shared__ int cols[HW];                  // compacted unflagged columns
  __shared__ int chunk_cnt[64];
  __shared__ int chunk_off[64];
  __shared__ int total_sh;
  __shared__ long long s[4];
  const int wave = threadIdx.x >> 6;
  const int lane = threadIdx.x & 63;

  // 64 chunks of 64 columns each; wave w handles chunks w, w+4, ...
#pragma unroll
  for (int t = wave; t < 64; t += 4) {
    const int j = t * 64 + lane;
    const unsigned long long bal = __ballot(mask[j] == 0);
    if (lane == 0) chunk_cnt[t] = __popcll(bal);
  }
  __syncthreads();
  if (wave == 0) {                          // 64-element scan by one wave
    int v = chunk_cnt[lane];
    int inc = v;
#pragma unroll
    for (int off = 1; off < 64; off <<= 1) {
      const int u = __shfl_up(inc, off);
      if (lane >= off) inc += u;
    }
    chunk_off[lane] = inc - v;              // exclusive
    if (lane == 63) total_sh = inc;
  }
  __syncthreads();
#pragma unroll
  for (int t = wave; t < 64; t += 4) {
    const int j = t * 64 + lane;
    const bool un = (mask[j] == 0);
    const unsigned long long bal = __ballot(un);
    if (un) {
      const int pos = chunk_off[t] + __popcll(bal & ((1ULL << lane) - 1ULL));
      cols[pos] = j;
    }
  }
  __syncthreads();

  const int m = total_sh;
  const int row0 = (p >> 1) * 2;
#pragma unroll
  for (int r = 0; r < 2; ++r) {
    const int i = row0 + r;
    if (mask[i] == 0) {                     // block-uniform branch
      if (threadIdx.x == 0) idx[i] = -1;    // reference discards this row
      continue;
    }
    const uint32_t e0 = (uint32_t)i * 4096u;
    long long best = -1;                    // ((bits>>9) << 12) | (4095 - j)
    for (int t = threadIdx.x; t < m; t += 256) {
      const int j = cols[t];
      const uint32_t bits = jax_bits32(e0 + (uint32_t)j);
      const long long k = ((long long)(bits >> 9) << 12) | (long long)(4095 - j);
      best = (k > best) ? k : best;
    }
#pragma unroll
    for (int off = 32; off > 0; off >>= 1) {
      const long long a = __shfl_down(best, off);
      best = (a > best) ? a : best;
    }
    if (lane == 0) s[wave] = best;
    __syncthreads();
    if (threadIdx.x == 0) {
      long long a = s[0];
#pragma unroll
      for (int w = 1; w < 4; ++w) if (s[w] > a) a = s[w];
      // m==0 (all columns NEG_INF) -> argmax==0, matches reference.
      idx[i] = (a >= 0) ? (4095 - (int)(a & 0xFFFLL)) : 0;
    }
    __syncthreads();                        // s[] reused next row
  }
}

// ---------------------------------------------------------------------------
// Kernel B (2048 blocks): latter plane (b,c), c in [0,256):
//   read x[b,256+c] ONCE -> write-through to out[b,256+c] AND stage in LDS,
//   then gather: out[b,512+c][j] = idx[j]>=0 ? lds[idx[j]] : 0.
// This keeps the single-pass latter read (no 33.5 MB second pass).
__global__ __launch_bounds__(256) void latter_gather_kernel(
    const float* __restrict__ x, const int* __restrict__ idx,
    float* __restrict__ out) {
  const int p = blockIdx.x;
  const int b = p >> 8, c = p & 255;
  const float4* src4 = (const float4*)(x + ((size_t)b * CC + C2 + c) * HW);
  float4* lat4 = (float4*)(out + ((size_t)b * OC + C2 + c) * HW);
  float4* shf4 = (float4*)(out + ((size_t)b * OC + 2 * C2 + c) * HW);
  __shared__ float lds[HW];
  float4* lds4 = (float4*)lds;
#pragma unroll
  for (int r = 0; r < 4; ++r) {
    const int t = threadIdx.x + r * 256;
    const float4 v = src4[t];
    lds4[t] = v;
    lat4[t] = v;                            // write-through copy of latter
  }
  __syncthreads();
  const int4* idx4 = (const int4*)idx;
#pragma unroll
  for (int r = 0; r < 4; ++r) {
    const int t = threadIdx.x + r * 256;
    const int4 nb = idx4[t];
    float4 v;
    v.x = (nb.x >= 0) ? lds[nb.x] : 0.0f;
    v.y = (nb.y >= 0) ? lds[nb.y] : 0.0f;
    v.z = (nb.z >= 0) ? lds[nb.z] : 0.0f;
    v.w = (nb.w >= 0) ? lds[nb.w] : 0.0f;
    shf4[t] = v;
  }
}

extern "C" void kernel_launch(void* const* d_in, const int* in_sizes, int n_in,
                              void* d_out, int out_size, void* d_ws, size_t ws_size,
                              hipStream_t stream) {
  const float* x  = (const float*)d_in[0];
  const int* mask = (const int*)d_in[1];
  float* out      = (float*)d_out;
  int* idx        = (int*)d_ws;             // [4096]

  former_idx_kernel<<<4096, 256, 0, stream>>>(x, mask, idx, out);
  latter_gather_kernel<<<2048, 256, 0, stream>>>(x, idx, out);
}

// Round 3
// 168.049 us; speedup vs baseline: 1.0704x; 1.0704x over previous
//
#include <hip/hip_runtime.h>
#include <stdint.h>

// x (8, 512, 64, 64) fp32, mask (64, 64) int32 -> out (8, 768, 64, 64) fp32
static constexpr int HW = 4096;   // 64*64
static constexpr int CC = 512;
static constexpr int C2 = 256;
static constexpr int OC = 768;

__device__ __forceinline__ uint32_t rotl32(uint32_t x, int d) {
  return (x << d) | (x >> (32 - d));
}

// JAX threefry2x32, key (0, 42)  [jax.random.key(42)]
__device__ __forceinline__ void threefry_0_42(uint32_t x0, uint32_t x1,
                                              uint32_t& o0, uint32_t& o1) {
  const uint32_t k0 = 0u;
  const uint32_t k1 = 42u;
  const uint32_t k2 = 0x1BD11BDAu ^ k0 ^ k1;   // 0x1BD11BF0
  x0 += k0; x1 += k1;
#define TF_ROUND(r) { x0 += x1; x1 = rotl32(x1, (r)); x1 ^= x0; }
  TF_ROUND(13) TF_ROUND(15) TF_ROUND(26) TF_ROUND(6)
  x0 += k1; x1 += k2 + 1u;
  TF_ROUND(17) TF_ROUND(29) TF_ROUND(16) TF_ROUND(24)
  x0 += k2; x1 += k0 + 2u;
  TF_ROUND(13) TF_ROUND(15) TF_ROUND(26) TF_ROUND(6)
  x0 += k0; x1 += k1 + 3u;
  TF_ROUND(17) TF_ROUND(29) TF_ROUND(16) TF_ROUND(24)
  x0 += k1; x1 += k2 + 4u;
  TF_ROUND(13) TF_ROUND(15) TF_ROUND(26) TF_ROUND(6)
  x0 += k2; x1 += k0 + 5u;
#undef TF_ROUND
  o0 = x0; o1 = x1;
}

// Partitionable threefry: counter (0, e), fold = xor of the two output lanes.
__device__ __forceinline__ uint32_t jax_bits32(uint32_t e) {
  uint32_t o0, o1;
  threefry_0_42(0u, e, o0, o1);
  return o0 ^ o1;
}

// ---------------------------------------------------------------------------
// Kernel 0 (1 block): compact unflagged columns (mask[j]==0) into cols_g,
// ascending j (required for the smallest-j tie-break), count into m_g.
// Hoisted here ONCE instead of being redone by every argmax block (round-0
// structure paid ~1-2 us of latency-bound ballots+scan+barriers per block).
__global__ __launch_bounds__(256) void compact_kernel(
    const int* __restrict__ mask, int* __restrict__ cols_g,
    int* __restrict__ m_g) {
  __shared__ int chunk_cnt[64];
  __shared__ int chunk_off[64];
  const int wave = threadIdx.x >> 6;
  const int lane = threadIdx.x & 63;

  // 64 chunks of 64 columns each; wave w handles chunks w, w+4, ...
#pragma unroll
  for (int t = wave; t < 64; t += 4) {
    const int j = t * 64 + lane;
    const unsigned long long bal = __ballot(mask[j] == 0);
    if (lane == 0) chunk_cnt[t] = __popcll(bal);
  }
  __syncthreads();
  if (wave == 0) {                          // 64-element scan by one wave
    int v = chunk_cnt[lane];
    int inc = v;
#pragma unroll
    for (int off = 1; off < 64; off <<= 1) {
      const int u = __shfl_up(inc, off);
      if (lane >= off) inc += u;
    }
    chunk_off[lane] = inc - v;              // exclusive
    if (lane == 63) *m_g = inc;
  }
  __syncthreads();
#pragma unroll
  for (int t = wave; t < 64; t += 4) {
    const int j = t * 64 + lane;
    const bool un = (mask[j] == 0);
    const unsigned long long bal = __ballot(un);
    if (un) {
      const int pos = chunk_off[t] + __popcll(bal & ((1ULL << lane) - 1ULL));
      cols_g[pos] = j;
    }
  }
}

// ---------------------------------------------------------------------------
// Kernel A (8192 blocks, round-0 even/odd role interleave — PROVEN at 163us):
//   even p: copy plane q=p/2 in [0,4096): out[b,ch] = x[b,ch], ch in [0,512)
//   odd  p: argmax row i=p/2: flag[i]==0 -> idx[i]=-1; else stream the
//     precompacted cols from L2 (no LDS, no barriers, no ballots) and take
//     the exact-integer threefry argmax (monotone in bits>>9, tie -> min j).
__global__ __launch_bounds__(256) void copy_argmax_kernel(
    const float* __restrict__ x, const int* __restrict__ mask,
    const int* __restrict__ cols_g, const int* __restrict__ m_g,
    int* __restrict__ idx, float* __restrict__ out) {
  const int p = blockIdx.x;
  if ((p & 1) == 0) {
    const int q = p >> 1;                   // 0..4095 copy planes
    const int b = q >> 9, ch = q & 511;
    const float4* src = (const float4*)(x + ((size_t)b * CC + ch) * HW);
    float4* dst = (float4*)(out + ((size_t)b * OC + ch) * HW);
#pragma unroll
    for (int r = 0; r < 4; ++r) {
      const int t = threadIdx.x + r * 256;
      dst[t] = src[t];
    }
    return;
  }
  const int i = p >> 1;                     // 0..4095 rows
  if (mask[i] == 0) {
    if (threadIdx.x == 0) idx[i] = -1;      // reference discards this row
    return;
  }

  const int m = *m_g;                       // uniform scalar load (L2)
  const uint32_t e0 = (uint32_t)i * 4096u;
  long long best = -1;                      // ((bits>>9) << 12) | (4095 - j)
  for (int t = threadIdx.x; t < m; t += 256) {
    const int j = cols_g[t];
    const uint32_t bits = jax_bits32(e0 + (uint32_t)j);
    const long long k = ((long long)(bits >> 9) << 12) | (long long)(4095 - j);
    best = (k > best) ? k : best;
  }
  const int wave = threadIdx.x >> 6;
  const int lane = threadIdx.x & 63;
#pragma unroll
  for (int off = 32; off > 0; off >>= 1) {
    const long long a = __shfl_down(best, off);
    best = (a > best) ? a : best;
  }
  __shared__ long long s[4];
  if (lane == 0) s[wave] = best;
  __syncthreads();
  if (threadIdx.x == 0) {
    long long a = s[0];
#pragma unroll
    for (int w = 1; w < 4; ++w) if (s[w] > a) a = s[w];
    // m==0 (all columns NEG_INF) -> argmax==0, matches reference.
    idx[i] = (a >= 0) ? (4095 - (int)(a & 0xFFFLL)) : 0;
  }
}

// ---------------------------------------------------------------------------
// Kernel B (2048 blocks): shift planes (b,c), c in [0,256):
//   out[b,512+c,j] = idx[j]>=0 ? x[b,256+c,idx[j]] : 0
// The 33.5 MB re-read of x's latter half is L3-resident after kernel A.
__global__ __launch_bounds__(256) void gather_kernel(const float* __restrict__ x,
                                                     const int* __restrict__ idx,
                                                     float* __restrict__ out) {
  const int p = blockIdx.x;
  const int b = p >> 8, c = p & 255;
  const float* row = x + ((size_t)b * CC + C2 + c) * HW;
  float* oshift = out + ((size_t)b * OC + 512 + c) * HW;
  __shared__ float lds[HW];
  const float4* row4 = (const float4*)row;
  float4* lds4 = (float4*)lds;
#pragma unroll
  for (int r = 0; r < 4; ++r) {
    const int t = threadIdx.x + r * 256;
    lds4[t] = row4[t];
  }
  __syncthreads();
  const int4* idx4 = (const int4*)idx;
  float4* oshift4 = (float4*)oshift;
#pragma unroll
  for (int r = 0; r < 4; ++r) {
    const int t = threadIdx.x + r * 256;
    const int4 nb = idx4[t];
    float4 v;
    v.x = (nb.x >= 0) ? lds[nb.x] : 0.0f;
    v.y = (nb.y >= 0) ? lds[nb.y] : 0.0f;
    v.z = (nb.z >= 0) ? lds[nb.z] : 0.0f;
    v.w = (nb.w >= 0) ? lds[nb.w] : 0.0f;
    oshift4[t] = v;
  }
}

extern "C" void kernel_launch(void* const* d_in, const int* in_sizes, int n_in,
                              void* d_out, int out_size, void* d_ws, size_t ws_size,
                              hipStream_t stream) {
  const float* x  = (const float*)d_in[0];
  const int* mask = (const int*)d_in[1];
  float* out      = (float*)d_out;
  int* idx        = (int*)d_ws;             // [4096]
  int* cols_g     = (int*)d_ws + 4096;      // [4096]
  int* m_g        = (int*)d_ws + 8192;      // [1]

  compact_kernel<<<1, 256, 0, stream>>>(mask, cols_g, m_g);
  copy_argmax_kernel<<<8192, 256, 0, stream>>>(x, mask, cols_g, m_g, idx, out);
  gather_kernel<<<2048, 256, 0, stream>>>(x, idx, out);
}